// Round 7
// baseline (296.611 us; speedup 1.0000x reference)
//
#include <hip/hip_runtime.h>
#include <stdint.h>

// Problem constants
#define B_SZ 4
#define S_LEN 2048
#define NH 16
#define HD 64
#define DM 1024

typedef __bf16 bf16;
typedef __bf16 bf16x4 __attribute__((ext_vector_type(4)));
typedef __bf16 bf16x8 __attribute__((ext_vector_type(8)));
typedef float f32x4 __attribute__((ext_vector_type(4)));

#define MFMA16(a, b, c) __builtin_amdgcn_mfma_f32_16x16x32_bf16(a, b, c, 0, 0, 0)

__device__ __forceinline__ void gl2lds16(const void* g, void* l) {
  __builtin_amdgcn_global_load_lds(
      (__attribute__((address_space(1))) const void*)g,
      (__attribute__((address_space(3))) void*)l, 16, 0, 0);
}

// load 8 consecutive f32 and round to bf16x8
__device__ __forceinline__ bf16x8 ldcvt(const float* p) {
  f32x4 u0 = *(const f32x4*)p;
  f32x4 u1 = *(const f32x4*)(p + 4);
  bf16x8 v;
#pragma unroll
  for (int j = 0; j < 4; j++) {
    v[j] = (bf16)u0[j];
    v[4 + j] = (bf16)u1[j];
  }
  return v;
}

// ---------------------------------------------------------------------------
// Kernel 0: f32 -> bf16 conversion of x-chunk and the 4 weight matrices.
// ---------------------------------------------------------------------------
__global__ void cvt_kernel(const float* __restrict__ x,
                           const float* __restrict__ wq,
                           const float* __restrict__ wk,
                           const float* __restrict__ wv,
                           const float* __restrict__ wo,
                           bf16* __restrict__ Xb, bf16* __restrict__ Wb,
                           long xN) {
  const long e = ((long)blockIdx.x * 256 + threadIdx.x) * 8;
  const float* src;
  bf16* dst;
  long off;
  if (e < xN) {
    src = x; dst = Xb; off = e;
  } else {
    const long w = e - xN;
    const int wi = (int)(w >> 20);  // 1M elems per weight
    src = (wi == 0) ? wq : (wi == 1) ? wk : (wi == 2) ? wv : wo;
    dst = Wb + ((size_t)wi << 20);
    off = w & ((1L << 20) - 1);
  }
  *(bf16x8*)(dst + off) = ldcvt(src + off);
}

// ---------------------------------------------------------------------------
// 128x128 GEMM core (m97 structure): BK=32, global_load_lds width-16,
// unpadded [128][32] LDS, 2 barriers/iter. C[m,n] = sum_k A[m,k]*B[n,k].
// ---------------------------------------------------------------------------
__device__ __forceinline__ void gemm_core_bb(const bf16* __restrict__ Ag,
                                             const bf16* __restrict__ Bg,
                                             f32x4 acc[4][4], bf16* As,
                                             bf16* Bs) {
  const int tid = threadIdx.x;
  const int lane = tid & 63;
  const int wave = tid >> 6;
  const int wm = (wave >> 1) * 64;
  const int wn = (wave & 1) * 64;
  const int col = lane & 15;
  const int kq = (lane >> 4) * 8;
  const int r0 = tid >> 2;       // staging row (pass 0)
  const int c0 = (tid & 3) * 8;  // staging col
#pragma unroll
  for (int i = 0; i < 4; i++)
#pragma unroll
    for (int j = 0; j < 4; j++) acc[i][j] = (f32x4){0.f, 0.f, 0.f, 0.f};

  for (int k0 = 0; k0 < 1024; k0 += 32) {
    __syncthreads();  // previous iteration's LDS reads complete
    gl2lds16(Ag + (size_t)r0 * 1024 + k0 + c0, As + tid * 8);
    gl2lds16(Ag + (size_t)(r0 + 64) * 1024 + k0 + c0, As + 2048 + tid * 8);
    gl2lds16(Bg + (size_t)r0 * 1024 + k0 + c0, Bs + tid * 8);
    gl2lds16(Bg + (size_t)(r0 + 64) * 1024 + k0 + c0, Bs + 2048 + tid * 8);
    __syncthreads();  // drains vmcnt -> LDS data visible

    bf16x8 af[4], bfr[4];
#pragma unroll
    for (int i = 0; i < 4; i++)
      af[i] = *(const bf16x8*)(As + (wm + i * 16 + col) * 32 + kq);
#pragma unroll
    for (int j = 0; j < 4; j++)
      bfr[j] = *(const bf16x8*)(Bs + (wn + j * 16 + col) * 32 + kq);
#pragma unroll
    for (int i = 0; i < 4; i++)
#pragma unroll
      for (int j = 0; j < 4; j++)
        acc[i][j] = MFMA16(af[i], bfr[j], acc[i][j]);
  }
}

// ---------------------------------------------------------------------------
// Kernel 1: fused QKV projection (bf16 in/out) + fused V transpose.
// grid (bcnt*16, 24). wsel 0/1 -> Q/K [bh][s][d]; wsel 2 -> Vt [bh][d][s].
// ---------------------------------------------------------------------------
__global__ __launch_bounds__(256, 4) void qkv_gemm(
    const bf16* __restrict__ x, const bf16* __restrict__ Wb,
    bf16* __restrict__ Q, bf16* __restrict__ K, bf16* __restrict__ Vt) {
  __shared__ __align__(16) bf16 As[128 * 32];
  __shared__ __align__(16) bf16 Bs[128 * 32];
  const int bx = blockIdx.x;
  const int by = blockIdx.y;
  const int wsel = by >> 3;
  const int n0 = (by & 7) * 128;

  f32x4 acc[4][4];
  gemm_core_bb(x + (size_t)bx * 128 * 1024,
               Wb + ((size_t)wsel << 20) + (size_t)n0 * 1024, acc, As, Bs);

  const int lane = threadIdx.x & 63;
  const int wave = threadIdx.x >> 6;
  const int wm = (wave >> 1) * 64, wn = (wave & 1) * 64;
  const int col = lane & 15, quad = lane >> 4;

  if (wsel < 2) {
    bf16* dst = wsel ? K : Q;
#pragma unroll
    for (int i = 0; i < 4; i++) {
      const int m0 = bx * 128 + wm + i * 16 + quad * 4;
#pragma unroll
      for (int j = 0; j < 4; j++) {
        const int n = n0 + wn + j * 16 + col;  // [0,1024)
        const int h = n >> 6, d = n & 63;
#pragma unroll
        for (int r = 0; r < 4; r++) {
          const int mm = m0 + r;  // pass-local row
          const int bl = mm >> 11, s = mm & 2047;
          dst[((((size_t)bl * NH + h) * S_LEN + s) << 6) + d] =
              (bf16)acc[i][j][r];
        }
      }
    }
  } else {  // V: write transposed [bh][d][s], 4 consecutive s per store
#pragma unroll
    for (int i = 0; i < 4; i++) {
      const int m0 = bx * 128 + wm + i * 16 + quad * 4;
      const int bl = m0 >> 11, s = m0 & 2047;
#pragma unroll
      for (int j = 0; j < 4; j++) {
        const int n = n0 + wn + j * 16 + col;
        const int h = n >> 6, d = n & 63;
        bf16x4 pk;
#pragma unroll
        for (int r = 0; r < 4; r++) pk[r] = (bf16)acc[i][j][r];
        *(bf16x4*)(Vt + (((size_t)(bl * NH + h) * 64 + d) << 11) + s) = pk;
      }
    }
  }
}

// ---------------------------------------------------------------------------
// Kernel 2: RoPE in-place on Q,K. Q additionally scaled by 0.125*log2(e)
// (folds the softmax scale + exp2 base conversion into the QK^T MFMA).
// ---------------------------------------------------------------------------
__global__ void rope_kernel(bf16* __restrict__ q, bf16* __restrict__ k,
                            const int* __restrict__ tp) {
  const float CS = 0.18033688011112042f;  // 0.125 * log2(e)
  const int idx = blockIdx.x * 256 + threadIdx.x;
  const int srow = idx >> 3;  // pass-local [0, bcnt*H*S)
  const int d0 = (idx & 7) * 8;
  const int s = srow & (S_LEN - 1);
  const float pf = (float)tp[s];
  const int i0 = d0 >> 1;
  float cs[4], sn[4];
#pragma unroll
  for (int j = 0; j < 4; j++) {
    float freq = __builtin_exp2f(-(float)(i0 + j) * 0.41524101186091903f);
    float ang = pf * freq;
    sincosf(ang, &sn[j], &cs[j]);
  }
  const size_t off = (size_t)srow * 64 + d0;
  bf16x8 vq = *(bf16x8*)(q + off);
  bf16x8 vk = *(bf16x8*)(k + off);
#pragma unroll
  for (int j = 0; j < 4; j++) {
    float e = (float)vq[2 * j], o = (float)vq[2 * j + 1];
    vq[2 * j] = (bf16)((e * cs[j] - o * sn[j]) * CS);
    vq[2 * j + 1] = (bf16)((e * sn[j] + o * cs[j]) * CS);
    e = (float)vk[2 * j];
    o = (float)vk[2 * j + 1];
    vk[2 * j] = (bf16)(e * cs[j] - o * sn[j]);
    vk[2 * j + 1] = (bf16)(e * sn[j] + o * cs[j]);
  }
  *(bf16x8*)(q + off) = vq;
  *(bf16x8*)(k + off) = vk;
}

// ---------------------------------------------------------------------------
// Kernel 4: BARRIER-FREE causal flash attention. grid (nbh, 8).
// x = bh (XCD = bh%8 -> per-XCD L2 holds its 8 bh's K+V = 4 MB), y = qpair:
// qt = y<4 ? 7-y : y-4 (co-resident pair y,y+4 sums to 7 -> balanced).
// 4 waves x 64 q-rows; K/V fragments read straight from global (L1/L2-
// served); only per-wave P buffer in LDS; NO __syncthreads anywhere.
// No max-tracking: P = exp2(s') directly (scale folded into Q via RoPE).
// ---------------------------------------------------------------------------
#define PP 72  // P row pitch
__global__ __launch_bounds__(256, 2) void attn_kernel(
    const bf16* __restrict__ Q, const bf16* __restrict__ K,
    const bf16* __restrict__ Vt, bf16* __restrict__ O) {
  __shared__ __align__(16) bf16 Ps[4 * 64 * PP];  // 36,864 B

  const int tid = threadIdx.x, lane = tid & 63, wave = tid >> 6;
  const int col = lane & 15, quad = lane >> 4, kq = quad * 8;
  const int bh = blockIdx.x;
  const int yb = blockIdx.y;
  const int qt = (yb < 4) ? (7 - yb) : (yb - 4);
  const int bl = bh >> 4, h = bh & 15;
  const bf16* Kg = K + (size_t)bh * S_LEN * 64;
  const bf16* Vg = Vt + (size_t)bh * 64 * S_LEN;
  bf16* Pw = Ps + wave * 64 * PP;
  const int wq_abs = qt * 256 + wave * 64;  // this wave's first q row

  // Q fragments: 4 m-tiles x (K=64 -> 2 chained), straight from global
  const bf16* Qg = Q + ((size_t)bh * S_LEN + wq_abs) * 64;
  bf16x8 qf[4][2];
#pragma unroll
  for (int mi = 0; mi < 4; mi++)
#pragma unroll
    for (int kc = 0; kc < 2; kc++)
      qf[mi][kc] =
          *(const bf16x8*)(Qg + (mi * 16 + col) * 64 + kc * 32 + kq);

  f32x4 oacc[4][4];
  float lst[4] = {0.f, 0.f, 0.f, 0.f};
#pragma unroll
  for (int mi = 0; mi < 4; mi++)
#pragma unroll
    for (int nd = 0; nd < 4; nd++) oacc[mi][nd] = (f32x4){0.f, 0.f, 0.f, 0.f};

  for (int kb = 0; kb <= wq_abs + 63; kb += 64) {
    // S^T[key][q]: A = K-frags from global, B = Q-frags (regs)
    f32x4 sa[4][4];
#pragma unroll
    for (int ni = 0; ni < 4; ni++) {
      const bf16* kr = Kg + (size_t)(kb + ni * 16 + col) * 64;
      bf16x8 kf0 = *(const bf16x8*)(kr + kq);
      bf16x8 kf1 = *(const bf16x8*)(kr + 32 + kq);
#pragma unroll
      for (int mi = 0; mi < 4; mi++) {
        f32x4 s = {0.f, 0.f, 0.f, 0.f};
        s = MFMA16(kf0, qf[mi][0], s);
        s = MFMA16(kf1, qf[mi][1], s);
        sa[mi][ni] = s;  // reg r: key = kb+ni*16+quad*4+r, q = wq_abs+mi*16+col
      }
    }
    if (kb + 63 > wq_abs) {  // diagonal band: elementwise causal mask
      const int base = kb - wq_abs + quad * 4;
#pragma unroll
      for (int mi = 0; mi < 4; mi++)
#pragma unroll
        for (int ni = 0; ni < 4; ni++)
#pragma unroll
          for (int r = 0; r < 4; r++)
            if (base + ni * 16 + r > mi * 16 + col) sa[mi][ni][r] = -1e30f;
    }
    // P = exp2(s'), lane-local partial l (cross-quad reduce deferred)
#pragma unroll
    for (int mi = 0; mi < 4; mi++) {
      float rs = 0.f;
#pragma unroll
      for (int ni = 0; ni < 4; ni++)
#pragma unroll
        for (int r = 0; r < 4; r++) {
          float pv = __builtin_exp2f(sa[mi][ni][r]);
          sa[mi][ni][r] = pv;
          rs += pv;
        }
      lst[mi] += rs;
    }
    // P -> per-wave LDS (C-layout -> A-layout), conflict-free b64 writes
#pragma unroll
    for (int mi = 0; mi < 4; mi++)
#pragma unroll
      for (int ni = 0; ni < 4; ni++) {
        bf16x4 pk;
#pragma unroll
        for (int r = 0; r < 4; r++) pk[r] = (bf16)sa[mi][ni][r];
        *(bf16x4*)(Pw + (mi * 16 + col) * PP + ni * 16 + quad * 4) = pk;
      }
    // O += P @ V: pf from per-wave LDS, vf straight from global Vt[d][s]
#pragma unroll
    for (int kcl = 0; kcl < 2; kcl++) {
      bf16x8 pf[4];
#pragma unroll
      for (int mi = 0; mi < 4; mi++)
        pf[mi] = *(const bf16x8*)(Pw + (mi * 16 + col) * PP + kcl * 32 + kq);
#pragma unroll
      for (int nd = 0; nd < 4; nd++) {
        bf16x8 vf = *(const bf16x8*)(Vg + (size_t)(nd * 16 + col) * S_LEN +
                                     kb + kcl * 32 + kq);
#pragma unroll
        for (int mi = 0; mi < 4; mi++)
          oacc[mi][nd] = MFMA16(pf[mi], vf, oacc[mi][nd]);
      }
    }
  }

  // Epilogue: reduce l across quads once, O = oacc / l
#pragma unroll
  for (int mi = 0; mi < 4; mi++) {
    float rs = lst[mi];
    rs += __shfl_xor(rs, 16);
    rs += __shfl_xor(rs, 32);
    const float il = 1.0f / rs;
    float linv[4];
#pragma unroll
    for (int r = 0; r < 4; r++) linv[r] = __shfl(il, quad * 4 + r);
    const int srow0 = wq_abs + mi * 16 + quad * 4;
#pragma unroll
    for (int nd = 0; nd < 4; nd++)
#pragma unroll
      for (int r = 0; r < 4; r++)
        O[(size_t)(bl * S_LEN + srow0 + r) * DM + h * 64 + nd * 16 + col] =
            (bf16)(oacc[mi][nd][r] * linv[r]);
  }
}

// ---------------------------------------------------------------------------
// Kernel 5: output projection (A bf16, W bf16, out f32). grid (bcnt*16, 8).
// ---------------------------------------------------------------------------
__global__ __launch_bounds__(256, 4) void out_gemm(const bf16* __restrict__ A,
                                                   const bf16* __restrict__ W,
                                                   float* __restrict__ out) {
  __shared__ __align__(16) bf16 As[128 * 32];
  __shared__ __align__(16) bf16 Bs[128 * 32];
  f32x4 acc[4][4];
  gemm_core_bb(A + (size_t)blockIdx.x * 128 * 1024,
               W + (size_t)blockIdx.y * 128 * 1024, acc, As, Bs);
  const int lane = threadIdx.x & 63;
  const int wave = threadIdx.x >> 6;
  const int wm = (wave >> 1) * 64, wn = (wave & 1) * 64;
  const int col = lane & 15, quad = lane >> 4;
#pragma unroll
  for (int i = 0; i < 4; i++) {
    const int m0 = blockIdx.x * 128 + wm + i * 16 + quad * 4;
#pragma unroll
    for (int j = 0; j < 4; j++) {
      const int n = blockIdx.y * 128 + wn + j * 16 + col;
#pragma unroll
      for (int r = 0; r < 4; r++)
        out[(size_t)(m0 + r) * DM + n] = acc[i][j][r];
    }
  }
}

// ---------------------------------------------------------------------------
extern "C" void kernel_launch(void* const* d_in, const int* in_sizes, int n_in,
                              void* d_out, int out_size, void* d_ws,
                              size_t ws_size, hipStream_t stream) {
  const float* x = (const float*)d_in[0];
  const int* tp = (const int*)d_in[1];
  const float* wq = (const float*)d_in[2];
  const float* wk = (const float*)d_in[3];
  const float* wv = (const float*)d_in[4];
  const float* wo = (const float*)d_in[5];
  float* out = (float*)d_out;
  bf16* wsb = (bf16*)d_ws;

  const size_t TENb = (size_t)NH * S_LEN * HD;  // 2M elems = per-batch tensor
  const size_t WSZ = 4ull * DM * DM;            // 4M elems (4 bf16 weights)
  int bcnt = 1;
  if (ws_size >= (4 * 4 * TENb + WSZ) * sizeof(bf16)) bcnt = 4;       // 72 MB
  else if (ws_size >= (4 * 2 * TENb + WSZ) * sizeof(bf16)) bcnt = 2;  // 40 MB

  const size_t REG = (size_t)bcnt * TENb;
  bf16* Xb = wsb;             // [bcnt,S,DM] bf16 x; later aliased by Ow
  bf16* Qw = wsb + REG;       // [bcnt,H,S,D]
  bf16* Kw = wsb + 2 * REG;   // [bcnt,H,S,D]
  bf16* Vtw = wsb + 3 * REG;  // [bcnt,H,D,S]
  bf16* Wb = wsb + 4 * REG;   // [4,DM,DM] bf16 weights (wq|wk|wv|wo)
  bf16* Ow = Xb;              // [bcnt,S,H*D], x dead after qkv_gemm

  for (int b0 = 0; b0 < B_SZ; b0 += bcnt) {
    const float* xb = x + (size_t)b0 * S_LEN * DM;
    float* outb = out + (size_t)b0 * S_LEN * DM;
    const long cvtN = (long)(REG + WSZ);  // elems, divisible by 2048
    hipLaunchKernelGGL(cvt_kernel, dim3((unsigned)(cvtN / 2048)), dim3(256), 0,
                       stream, xb, wq, wk, wv, wo, Xb, Wb, (long)REG);
    hipLaunchKernelGGL(qkv_gemm, dim3(bcnt * 16, 24), dim3(256), 0, stream,
                       Xb, Wb, Qw, Kw, Vtw);
    hipLaunchKernelGGL(rope_kernel, dim3(bcnt * 1024), dim3(256), 0, stream,
                       Qw, Kw, tp);
    hipLaunchKernelGGL(attn_kernel, dim3(bcnt * 16, 8), dim3(256), 0, stream,
                       Qw, Kw, Vtw, Ow);
    hipLaunchKernelGGL(out_gemm, dim3(bcnt * 16, 8), dim3(256), 0, stream,
                       Ow, Wb + 3ull * DM * DM, outb);
  }
}

// Round 8
// 276.817 us; speedup vs baseline: 1.0715x; 1.0715x over previous
//
#include <hip/hip_runtime.h>
#include <stdint.h>

// Problem constants
#define B_SZ 4
#define S_LEN 2048
#define NH 16
#define HD 64
#define DM 1024

typedef __bf16 bf16;
typedef __bf16 bf16x4 __attribute__((ext_vector_type(4)));
typedef __bf16 bf16x8 __attribute__((ext_vector_type(8)));
typedef float f32x4 __attribute__((ext_vector_type(4)));

#define MFMA16(a, b, c) __builtin_amdgcn_mfma_f32_16x16x32_bf16(a, b, c, 0, 0, 0)

__device__ __forceinline__ void gl2lds16(const void* g, void* l) {
  __builtin_amdgcn_global_load_lds(
      (__attribute__((address_space(1))) const void*)g,
      (__attribute__((address_space(3))) void*)l, 16, 0, 0);
}

// Barrier that orders LDS (lgkm) only — does NOT drain vmcnt, so global
// loads prefetched for the next tile stay in flight across it.
__device__ __forceinline__ void bar_lgkm() {
  asm volatile("s_waitcnt lgkmcnt(0)\n\ts_barrier" ::: "memory");
}

// load 8 consecutive f32 and round to bf16x8
__device__ __forceinline__ bf16x8 ldcvt(const float* p) {
  f32x4 u0 = *(const f32x4*)p;
  f32x4 u1 = *(const f32x4*)(p + 4);
  bf16x8 v;
#pragma unroll
  for (int j = 0; j < 4; j++) {
    v[j] = (bf16)u0[j];
    v[4 + j] = (bf16)u1[j];
  }
  return v;
}

// ---------------------------------------------------------------------------
// Kernel 0: f32 -> bf16 conversion of x-chunk and the 4 weight matrices.
// ---------------------------------------------------------------------------
__global__ void cvt_kernel(const float* __restrict__ x,
                           const float* __restrict__ wq,
                           const float* __restrict__ wk,
                           const float* __restrict__ wv,
                           const float* __restrict__ wo,
                           bf16* __restrict__ Xb, bf16* __restrict__ Wb,
                           long xN) {
  const long e = ((long)blockIdx.x * 256 + threadIdx.x) * 8;
  const float* src;
  bf16* dst;
  long off;
  if (e < xN) {
    src = x; dst = Xb; off = e;
  } else {
    const long w = e - xN;
    const int wi = (int)(w >> 20);  // 1M elems per weight
    src = (wi == 0) ? wq : (wi == 1) ? wk : (wi == 2) ? wv : wo;
    dst = Wb + ((size_t)wi << 20);
    off = w & ((1L << 20) - 1);
  }
  *(bf16x8*)(dst + off) = ldcvt(src + off);
}

// ---------------------------------------------------------------------------
// 128x128 GEMM core (m97 structure): BK=32, global_load_lds width-16,
// unpadded [128][32] LDS, 2 barriers/iter. C[m,n] = sum_k A[m,k]*B[n,k].
// ---------------------------------------------------------------------------
__device__ __forceinline__ void gemm_core_bb(const bf16* __restrict__ Ag,
                                             const bf16* __restrict__ Bg,
                                             f32x4 acc[4][4], bf16* As,
                                             bf16* Bs) {
  const int tid = threadIdx.x;
  const int lane = tid & 63;
  const int wave = tid >> 6;
  const int wm = (wave >> 1) * 64;
  const int wn = (wave & 1) * 64;
  const int col = lane & 15;
  const int kq = (lane >> 4) * 8;
  const int r0 = tid >> 2;       // staging row (pass 0)
  const int c0 = (tid & 3) * 8;  // staging col
#pragma unroll
  for (int i = 0; i < 4; i++)
#pragma unroll
    for (int j = 0; j < 4; j++) acc[i][j] = (f32x4){0.f, 0.f, 0.f, 0.f};

  for (int k0 = 0; k0 < 1024; k0 += 32) {
    __syncthreads();  // previous iteration's LDS reads complete
    gl2lds16(Ag + (size_t)r0 * 1024 + k0 + c0, As + tid * 8);
    gl2lds16(Ag + (size_t)(r0 + 64) * 1024 + k0 + c0, As + 2048 + tid * 8);
    gl2lds16(Bg + (size_t)r0 * 1024 + k0 + c0, Bs + tid * 8);
    gl2lds16(Bg + (size_t)(r0 + 64) * 1024 + k0 + c0, Bs + 2048 + tid * 8);
    __syncthreads();  // drains vmcnt -> LDS data visible

    bf16x8 af[4], bfr[4];
#pragma unroll
    for (int i = 0; i < 4; i++)
      af[i] = *(const bf16x8*)(As + (wm + i * 16 + col) * 32 + kq);
#pragma unroll
    for (int j = 0; j < 4; j++)
      bfr[j] = *(const bf16x8*)(Bs + (wn + j * 16 + col) * 32 + kq);
#pragma unroll
    for (int i = 0; i < 4; i++)
#pragma unroll
      for (int j = 0; j < 4; j++)
        acc[i][j] = MFMA16(af[i], bfr[j], acc[i][j]);
  }
}

// ---------------------------------------------------------------------------
// Kernel 1: fused QKV projection (bf16 in/out) + fused V transpose.
// grid (bcnt*16, 24). wsel 0/1 -> Q/K [bh][s][d]; wsel 2 -> Vt [bh][d][s].
// ---------------------------------------------------------------------------
__global__ __launch_bounds__(256, 4) void qkv_gemm(
    const bf16* __restrict__ x, const bf16* __restrict__ Wb,
    bf16* __restrict__ Q, bf16* __restrict__ K, bf16* __restrict__ Vt) {
  __shared__ __align__(16) bf16 As[128 * 32];
  __shared__ __align__(16) bf16 Bs[128 * 32];
  const int bx = blockIdx.x;
  const int by = blockIdx.y;
  const int wsel = by >> 3;
  const int n0 = (by & 7) * 128;

  f32x4 acc[4][4];
  gemm_core_bb(x + (size_t)bx * 128 * 1024,
               Wb + ((size_t)wsel << 20) + (size_t)n0 * 1024, acc, As, Bs);

  const int lane = threadIdx.x & 63;
  const int wave = threadIdx.x >> 6;
  const int wm = (wave >> 1) * 64, wn = (wave & 1) * 64;
  const int col = lane & 15, quad = lane >> 4;

  if (wsel < 2) {
    bf16* dst = wsel ? K : Q;
#pragma unroll
    for (int i = 0; i < 4; i++) {
      const int m0 = bx * 128 + wm + i * 16 + quad * 4;
#pragma unroll
      for (int j = 0; j < 4; j++) {
        const int n = n0 + wn + j * 16 + col;  // [0,1024)
        const int h = n >> 6, d = n & 63;
#pragma unroll
        for (int r = 0; r < 4; r++) {
          const int mm = m0 + r;  // pass-local row
          const int bl = mm >> 11, s = mm & 2047;
          dst[((((size_t)bl * NH + h) * S_LEN + s) << 6) + d] =
              (bf16)acc[i][j][r];
        }
      }
    }
  } else {  // V: write transposed [bh][d][s], 4 consecutive s per store
#pragma unroll
    for (int i = 0; i < 4; i++) {
      const int m0 = bx * 128 + wm + i * 16 + quad * 4;
      const int bl = m0 >> 11, s = m0 & 2047;
#pragma unroll
      for (int j = 0; j < 4; j++) {
        const int n = n0 + wn + j * 16 + col;
        const int h = n >> 6, d = n & 63;
        bf16x4 pk;
#pragma unroll
        for (int r = 0; r < 4; r++) pk[r] = (bf16)acc[i][j][r];
        *(bf16x4*)(Vt + (((size_t)(bl * NH + h) * 64 + d) << 11) + s) = pk;
      }
    }
  }
}

// ---------------------------------------------------------------------------
// Kernel 2: RoPE in-place on Q,K. Q additionally scaled by 0.125*log2(e)
// (folds the softmax scale + exp2 base conversion into the QK^T MFMA).
// ---------------------------------------------------------------------------
__global__ void rope_kernel(bf16* __restrict__ q, bf16* __restrict__ k,
                            const int* __restrict__ tp) {
  const float CS = 0.18033688011112042f;  // 0.125 * log2(e)
  const int idx = blockIdx.x * 256 + threadIdx.x;
  const int srow = idx >> 3;  // pass-local [0, bcnt*H*S)
  const int d0 = (idx & 7) * 8;
  const int s = srow & (S_LEN - 1);
  const float pf = (float)tp[s];
  const int i0 = d0 >> 1;
  float cs[4], sn[4];
#pragma unroll
  for (int j = 0; j < 4; j++) {
    float freq = __builtin_exp2f(-(float)(i0 + j) * 0.41524101186091903f);
    float ang = pf * freq;
    sincosf(ang, &sn[j], &cs[j]);
  }
  const size_t off = (size_t)srow * 64 + d0;
  bf16x8 vq = *(bf16x8*)(q + off);
  bf16x8 vk = *(bf16x8*)(k + off);
#pragma unroll
  for (int j = 0; j < 4; j++) {
    float e = (float)vq[2 * j], o = (float)vq[2 * j + 1];
    vq[2 * j] = (bf16)((e * cs[j] - o * sn[j]) * CS);
    vq[2 * j + 1] = (bf16)((e * sn[j] + o * cs[j]) * CS);
    e = (float)vk[2 * j];
    o = (float)vk[2 * j + 1];
    vk[2 * j] = (bf16)(e * cs[j] - o * sn[j]);
    vk[2 * j + 1] = (bf16)(e * sn[j] + o * cs[j]);
  }
  *(bf16x8*)(q + off) = vq;
  *(bf16x8*)(k + off) = vk;
}

// ---------------------------------------------------------------------------
// Kernel 4: causal flash attention, LDS-staged K/V with SOFTWARE-PIPELINED
// register prefetch across vmcnt-free barriers (s_waitcnt lgkmcnt(0) +
// s_barrier only — global loads for tile kt+1 stay in flight through the
// compute of tile kt). grid (nbh, 8): x = bh (XCD = bh%8 -> per-XCD L2
// holds its 8 bh's K+V = 4 MB), y pairing qt = y<4 ? 7-y : y-4 (co-resident
// ids c, c+256 differ by 4 in y -> qt sums 7, balanced).
// 4 waves x 64 q-rows (256 q/block). No max-tracking softmax (scale folded
// into Q via RoPE); l reduced across quads once at epilogue.
// ---------------------------------------------------------------------------
#define KP 72   // Ks row pitch
#define VP 136  // Vts row pitch
#define PP 72   // P row pitch
__global__ __launch_bounds__(256, 2) void attn_kernel(
    const bf16* __restrict__ Q, const bf16* __restrict__ K,
    const bf16* __restrict__ Vt, bf16* __restrict__ O) {
  __shared__ __align__(16) bf16 Ks[128 * KP];     // 18432 B
  __shared__ __align__(16) bf16 Vts[64 * VP];     // 17408 B
  __shared__ __align__(16) bf16 Ps[4 * 64 * PP];  // 36864 B

  const int tid = threadIdx.x, lane = tid & 63, wave = tid >> 6;
  const int col = lane & 15, quad = lane >> 4, kq = quad * 8;
  const int bh = blockIdx.x;
  const int yb = blockIdx.y;
  const int qt = (yb < 4) ? (7 - yb) : (yb - 4);
  const int bl = bh >> 4, h = bh & 15;
  const bf16* Kg = K + (size_t)bh * S_LEN * 64;
  const bf16* Vg = Vt + (size_t)bh * 64 * S_LEN;
  bf16* Pw = Ps + wave * 64 * PP;
  const int wq_abs = qt * 256 + wave * 64;  // this wave's first q row
  const int qmax = wq_abs + 63;

  // Q fragments: 4 m-tiles x (K=64 -> 2 chained), straight from global
  const bf16* Qg = Q + ((size_t)bh * S_LEN + wq_abs) * 64;
  bf16x8 qf[4][2];
#pragma unroll
  for (int mi = 0; mi < 4; mi++)
#pragma unroll
    for (int kc = 0; kc < 2; kc++)
      qf[mi][kc] =
          *(const bf16x8*)(Qg + (mi * 16 + col) * 64 + kc * 32 + kq);

  f32x4 oacc[4][4];
  float lst[4] = {0.f, 0.f, 0.f, 0.f};
#pragma unroll
  for (int mi = 0; mi < 4; mi++)
#pragma unroll
    for (int nd = 0; nd < 4; nd++) oacc[mi][nd] = (f32x4){0.f, 0.f, 0.f, 0.f};

  const int kiters = 2 * qt + 2;
  // software pipeline: preload kt=0 into registers
  bf16x8 kreg[4], vreg[4];
#pragma unroll
  for (int p = 0; p < 4; p++) {
    const int g = p * 256 + tid;
    kreg[p] = *(const bf16x8*)(Kg + (size_t)(g >> 3) * 64 + (g & 7) * 8);
    vreg[p] = *(const bf16x8*)(Vg + (size_t)(g >> 4) * S_LEN + (g & 15) * 8);
  }

  for (int kt = 0; kt < kiters; kt++) {
    bar_lgkm();  // all waves done reading LDS from previous tile
#pragma unroll
    for (int p = 0; p < 4; p++) {  // compiler waits vmcnt for kreg/vreg here
      const int g = p * 256 + tid;
      *(bf16x8*)(Ks + (g >> 3) * KP + (g & 7) * 8) = kreg[p];
      *(bf16x8*)(Vts + (g >> 4) * VP + (g & 15) * 8) = vreg[p];
    }
    if (kt + 1 < kiters) {  // prefetch next tile; stays in flight past barrier
#pragma unroll
      for (int p = 0; p < 4; p++) {
        const int g = p * 256 + tid;
        kreg[p] = *(const bf16x8*)(Kg + (size_t)((kt + 1) * 128 + (g >> 3)) * 64 +
                                   (g & 7) * 8);
        vreg[p] = *(const bf16x8*)(Vg + (size_t)(g >> 4) * S_LEN +
                                   (kt + 1) * 128 + (g & 15) * 8);
      }
    }
    bar_lgkm();  // ds_writes visible to all waves (no vmcnt drain!)
    if (kt * 128 > qmax) continue;  // all keys masked for this wave

#pragma unroll
    for (int hf = 0; hf < 2; hf++) {
      const int kb = kt * 128 + hf * 64;  // first key of this 64-key chunk
      if (kb > qmax) break;               // wave-uniform
      // S^T[key][q] for 64 keys x 64 q
      f32x4 sa[4][4];
#pragma unroll
      for (int ni = 0; ni < 4; ni++) {
        const int krow = hf * 64 + ni * 16 + col;
        bf16x8 kf0 = *(const bf16x8*)(Ks + krow * KP + kq);
        bf16x8 kf1 = *(const bf16x8*)(Ks + krow * KP + 32 + kq);
#pragma unroll
        for (int mi = 0; mi < 4; mi++) {
          f32x4 s = {0.f, 0.f, 0.f, 0.f};
          s = MFMA16(kf0, qf[mi][0], s);
          s = MFMA16(kf1, qf[mi][1], s);
          sa[mi][ni] = s;  // reg r: key = kb+ni*16+quad*4+r, q = wq_abs+mi*16+col
        }
      }
      if (kb + 63 > wq_abs) {  // diagonal band: elementwise causal mask
        const int base = kb - wq_abs + quad * 4;
#pragma unroll
        for (int mi = 0; mi < 4; mi++)
#pragma unroll
          for (int ni = 0; ni < 4; ni++)
#pragma unroll
            for (int r = 0; r < 4; r++)
              if (base + ni * 16 + r > mi * 16 + col) sa[mi][ni][r] = -1e30f;
      }
      // P = exp2(s'), lane-local partial l (cross-quad reduce deferred)
#pragma unroll
      for (int mi = 0; mi < 4; mi++) {
        float rs = 0.f;
#pragma unroll
        for (int ni = 0; ni < 4; ni++)
#pragma unroll
          for (int r = 0; r < 4; r++) {
            float pv = __builtin_exp2f(sa[mi][ni][r]);
            sa[mi][ni][r] = pv;
            rs += pv;
          }
        lst[mi] += rs;
      }
      // P -> per-wave LDS (C-layout -> A-layout), conflict-free b64 writes
#pragma unroll
      for (int mi = 0; mi < 4; mi++)
#pragma unroll
        for (int ni = 0; ni < 4; ni++) {
          bf16x4 pk;
#pragma unroll
          for (int r = 0; r < 4; r++) pk[r] = (bf16)sa[mi][ni][r];
          *(bf16x4*)(Pw + (mi * 16 + col) * PP + ni * 16 + quad * 4) = pk;
        }
      // O += P @ V for this 64-key chunk (2 MFMA k-steps)
#pragma unroll
      for (int kcl = 0; kcl < 2; kcl++) {
        bf16x8 pf[4];
#pragma unroll
        for (int mi = 0; mi < 4; mi++)
          pf[mi] = *(const bf16x8*)(Pw + (mi * 16 + col) * PP + kcl * 32 + kq);
#pragma unroll
        for (int nd = 0; nd < 4; nd++) {
          bf16x8 vf = *(const bf16x8*)(Vts + (nd * 16 + col) * VP + hf * 64 +
                                       kcl * 32 + kq);
#pragma unroll
          for (int mi = 0; mi < 4; mi++)
            oacc[mi][nd] = MFMA16(pf[mi], vf, oacc[mi][nd]);
        }
      }
    }
  }

  // Epilogue: reduce l across quads once, O = oacc / l
#pragma unroll
  for (int mi = 0; mi < 4; mi++) {
    float rs = lst[mi];
    rs += __shfl_xor(rs, 16);
    rs += __shfl_xor(rs, 32);
    const float il = 1.0f / rs;
    float linv[4];
#pragma unroll
    for (int r = 0; r < 4; r++) linv[r] = __shfl(il, quad * 4 + r);
    const int srow0 = wq_abs + mi * 16 + quad * 4;
#pragma unroll
    for (int nd = 0; nd < 4; nd++)
#pragma unroll
      for (int r = 0; r < 4; r++)
        O[(size_t)(bl * S_LEN + srow0 + r) * DM + h * 64 + nd * 16 + col] =
            (bf16)(oacc[mi][nd][r] * linv[r]);
  }
}

// ---------------------------------------------------------------------------
// Kernel 5: output projection (A bf16, W bf16, out f32). grid (bcnt*16, 8).
// ---------------------------------------------------------------------------
__global__ __launch_bounds__(256, 4) void out_gemm(const bf16* __restrict__ A,
                                                   const bf16* __restrict__ W,
                                                   float* __restrict__ out) {
  __shared__ __align__(16) bf16 As[128 * 32];
  __shared__ __align__(16) bf16 Bs[128 * 32];
  f32x4 acc[4][4];
  gemm_core_bb(A + (size_t)blockIdx.x * 128 * 1024,
               W + (size_t)blockIdx.y * 128 * 1024, acc, As, Bs);
  const int lane = threadIdx.x & 63;
  const int wave = threadIdx.x >> 6;
  const int wm = (wave >> 1) * 64, wn = (wave & 1) * 64;
  const int col = lane & 15, quad = lane >> 4;
#pragma unroll
  for (int i = 0; i < 4; i++) {
    const int m0 = blockIdx.x * 128 + wm + i * 16 + quad * 4;
#pragma unroll
    for (int j = 0; j < 4; j++) {
      const int n = blockIdx.y * 128 + wn + j * 16 + col;
#pragma unroll
      for (int r = 0; r < 4; r++)
        out[(size_t)(m0 + r) * DM + n] = acc[i][j][r];
    }
  }
}

// ---------------------------------------------------------------------------
extern "C" void kernel_launch(void* const* d_in, const int* in_sizes, int n_in,
                              void* d_out, int out_size, void* d_ws,
                              size_t ws_size, hipStream_t stream) {
  const float* x = (const float*)d_in[0];
  const int* tp = (const int*)d_in[1];
  const float* wq = (const float*)d_in[2];
  const float* wk = (const float*)d_in[3];
  const float* wv = (const float*)d_in[4];
  const float* wo = (const float*)d_in[5];
  float* out = (float*)d_out;
  bf16* wsb = (bf16*)d_ws;

  const size_t TENb = (size_t)NH * S_LEN * HD;  // 2M elems = per-batch tensor
  const size_t WSZ = 4ull * DM * DM;            // 4M elems (4 bf16 weights)
  int bcnt = 1;
  if (ws_size >= (4 * 4 * TENb + WSZ) * sizeof(bf16)) bcnt = 4;       // 72 MB
  else if (ws_size >= (4 * 2 * TENb + WSZ) * sizeof(bf16)) bcnt = 2;  // 40 MB

  const size_t REG = (size_t)bcnt * TENb;
  bf16* Xb = wsb;             // [bcnt,S,DM] bf16 x; later aliased by Ow
  bf16* Qw = wsb + REG;       // [bcnt,H,S,D]
  bf16* Kw = wsb + 2 * REG;   // [bcnt,H,S,D]
  bf16* Vtw = wsb + 3 * REG;  // [bcnt,H,D,S]
  bf16* Wb = wsb + 4 * REG;   // [4,DM,DM] bf16 weights (wq|wk|wv|wo)
  bf16* Ow = Xb;              // [bcnt,S,H*D], x dead after qkv_gemm

  for (int b0 = 0; b0 < B_SZ; b0 += bcnt) {
    const float* xb = x + (size_t)b0 * S_LEN * DM;
    float* outb = out + (size_t)b0 * S_LEN * DM;
    const long cvtN = (long)(REG + WSZ);  // elems, divisible by 2048
    hipLaunchKernelGGL(cvt_kernel, dim3((unsigned)(cvtN / 2048)), dim3(256), 0,
                       stream, xb, wq, wk, wv, wo, Xb, Wb, (long)REG);
    hipLaunchKernelGGL(qkv_gemm, dim3(bcnt * 16, 24), dim3(256), 0, stream,
                       Xb, Wb, Qw, Kw, Vtw);
    hipLaunchKernelGGL(rope_kernel, dim3(bcnt * 1024), dim3(256), 0, stream,
                       Qw, Kw, tp);
    hipLaunchKernelGGL(attn_kernel, dim3(bcnt * 16, 8), dim3(256), 0, stream,
                       Qw, Kw, Vtw, Ow);
    hipLaunchKernelGGL(out_gemm, dim3(bcnt * 16, 8), dim3(256), 0, stream,
                       Ow, Wb + 3ull * DM * DM, outb);
  }
}